// Round 9
// baseline (989.635 us; speedup 1.0000x reference)
//
#include <hip/hip_runtime.h>
#include <hip/hip_fp16.h>

#define F 64
#define BSH 7            // bucket = 128 dst nodes
#define BN 128
#define NBMAX 2048       // supports N <= 262144
#define CHUNK 4096       // edges per partition block
#define CAPSH 11         // 2048 slots/bucket (mean fill ~1280 at E=1M,N=100k)
#define CAP (1 << CAPSH)
#define MMROWS 128
#define XT_PAD 132
#define APAD 68          // acc row pad (floats): 272 B rows, 16 B aligned

// ---- p1: partition edges into fixed-stride dst-buckets, packed (dstlo<<24)|src ----
__global__ __launch_bounds__(256) void partition_edges(const int* __restrict__ src,
                                                       const int* __restrict__ dst,
                                                       unsigned* __restrict__ bcnt,
                                                       unsigned* __restrict__ part,
                                                       int E, int NB) {
    __shared__ unsigned lh[NBMAX];
    __shared__ unsigned lbase[NBMAX];
    int t = threadIdx.x;
    int e0 = blockIdx.x * CHUNK;
    int e1 = min(e0 + CHUNK, E);
    for (int b = t; b < NB; b += 256) lh[b] = 0;
    __syncthreads();
    for (int e = e0 + t; e < e1; e += 256)
        atomicAdd(&lh[((unsigned)dst[e]) >> BSH], 1u);
    __syncthreads();
    for (int b = t; b < NB; b += 256) {
        unsigned c = lh[b];
        lbase[b] = c ? atomicAdd(&bcnt[b], c) : 0u;
        lh[b] = 0;  // reuse as local cursor
    }
    __syncthreads();
    for (int e = e0 + t; e < e1; e += 256) {
        unsigned d = (unsigned)dst[e];
        unsigned b = d >> BSH;
        unsigned pos = lbase[b] + atomicAdd(&lh[b], 1u);
        if (pos < CAP)
            part[((size_t)b << CAPSH) + pos] = ((d & (BN - 1u)) << 24) | (unsigned)src[e];
    }
}

// ---- p2: per-bucket degree histogram -> dinv only (no CSR scatter) ----
__global__ __launch_bounds__(256) void build_deg(const unsigned* __restrict__ part,
                                                 const unsigned* __restrict__ bcnt,
                                                 float* __restrict__ dinv, int N) {
    __shared__ unsigned cnt[BN];
    int t = threadIdx.x, b = blockIdx.x;
    if (t < BN) cnt[t] = 0;
    __syncthreads();
    unsigned m0 = (unsigned)b << CAPSH;
    unsigned m1 = m0 + min(bcnt[b], (unsigned)CAP);
    for (unsigned j = m0 + t; j < m1; j += 256)
        atomicAdd(&cnt[part[j] >> 24], 1u);
    __syncthreads();
    int v = (b << BSH) + t;
    if (t < BN && v < N) dinv[v] = rsqrtf((float)(cnt[t] + 1u));
}

// ---- Y[N,64](f16) = (X[N,64] @ W[64,64]) * dinv[row]; X fp32 ----
__global__ __launch_bounds__(256) void mm64_f16(const float* __restrict__ Xf,
                                                const float* __restrict__ W,
                                                const float* __restrict__ dinv,
                                                __half2* __restrict__ Y, int N) {
    __shared__ float Ws[64 * 64];       // 16 KB
    __shared__ float XT[64 * XT_PAD];   // X^T tile [k][r], 33 KB
    int t = threadIdx.x;
    for (int i = t; i < 1024; i += 256)
        ((float4*)Ws)[i] = ((const float4*)W)[i];
    int row0 = blockIdx.x * MMROWS;
    for (int i = t; i < MMROWS * 16; i += 256) {
        int r = i >> 4, kc = (i & 15) * 4;
        float4 v = make_float4(0.f, 0.f, 0.f, 0.f);
        int gr = row0 + r;
        if (gr < N) v = *(const float4*)(Xf + (size_t)gr * F + kc);
        XT[(kc + 0) * XT_PAD + r] = v.x;
        XT[(kc + 1) * XT_PAD + r] = v.y;
        XT[(kc + 2) * XT_PAD + r] = v.z;
        XT[(kc + 3) * XT_PAD + r] = v.w;
    }
    __syncthreads();
    int ty = t >> 3, tx = t & 7;
    float acc[4][8];
#pragma unroll
    for (int i = 0; i < 4; ++i)
#pragma unroll
        for (int j = 0; j < 8; ++j) acc[i][j] = 0.f;
#pragma unroll 4
    for (int k = 0; k < 64; ++k) {
        float4 xr = *(const float4*)&XT[k * XT_PAD + ty * 4];
        float4 w0 = *(const float4*)&Ws[k * 64 + tx * 8];
        float4 w1 = *(const float4*)&Ws[k * 64 + tx * 8 + 4];
        const float* xv = &xr.x;
#pragma unroll
        for (int i = 0; i < 4; ++i) {
            float xs = xv[i];
            acc[i][0] += xs * w0.x; acc[i][1] += xs * w0.y;
            acc[i][2] += xs * w0.z; acc[i][3] += xs * w0.w;
            acc[i][4] += xs * w1.x; acc[i][5] += xs * w1.y;
            acc[i][6] += xs * w1.z; acc[i][7] += xs * w1.w;
        }
    }
#pragma unroll
    for (int i = 0; i < 4; ++i) {
        int gr = row0 + ty * 4 + i;
        if (gr >= N) continue;
        float dv = dinv[gr];
        __half2 h[4];
#pragma unroll
        for (int j = 0; j < 4; ++j)
            h[j] = __floats2half2_rn(acc[i][2 * j] * dv, acc[i][2 * j + 1] * dv);
        *reinterpret_cast<uint4*>(Y + (size_t)gr * 32 + tx * 4) =
            *reinterpret_cast<uint4*>(h);
    }
}

// ---- LDS-accumulate aggregation over one 128-node bucket.
// MM=1: epilogue relu(out1) in LDS, then g2=(out1@W2)*dinv -> Y (f16).
// MM=0: epilogue writes out = sum*dinv + b (fp32) directly.
template <int MM>
__global__ __launch_bounds__(256) void agg(const unsigned* __restrict__ part,
                                           const unsigned* __restrict__ bcnt,
                                           const uint4* __restrict__ G,
                                           const float* __restrict__ dinv,
                                           const float* __restrict__ bias,
                                           const float* __restrict__ W,
                                           void* __restrict__ Y, int N) {
    __shared__ float acc[BN][APAD];           // 34.8 KB
    __shared__ float Ws[MM ? 64 * 64 : 4];    // 16 KB when fused mm
    __shared__ float dvs[BN];
    int t = threadIdx.x;
    for (int i = t; i < BN * APAD; i += 256) (&acc[0][0])[i] = 0.f;
    if (MM)
        for (int i = t; i < 1024; i += 256)
            ((float4*)Ws)[i] = ((const float4*)W)[i];
    __syncthreads();

    int v0 = blockIdx.x << BSH;
    unsigned m0 = (unsigned)blockIdx.x << CAPSH;
    unsigned m1 = m0 + min(bcnt[blockIdx.x], (unsigned)CAP);
    int l8 = t & 7;          // lane owns floats [l8*8, l8*8+8) of a row
    unsigned j = m0 + (t >> 3);   // 32 edge-groups per block, stride 32
    // 8-deep unrolled main loop: 256 edges per block-iteration
    for (; j + 224 < m1; j += 256) {
        unsigned p[8];
#pragma unroll
        for (int i = 0; i < 8; ++i) p[i] = part[j + i * 32];
        uint4 u[8];
#pragma unroll
        for (int i = 0; i < 8; ++i)
            u[i] = G[(size_t)(p[i] & 0xFFFFFFu) * 8 + l8];
#pragma unroll
        for (int i = 0; i < 8; ++i) {
            float* row = &acc[p[i] >> 24][l8 * 8];
            const __half2* hp = (const __half2*)&u[i];
#pragma unroll
            for (int q = 0; q < 4; ++q) {
                float2 f = __half22float2(hp[q]);
                atomicAdd(row + 2 * q, f.x);
                atomicAdd(row + 2 * q + 1, f.y);
            }
        }
    }
    for (; j < m1; j += 32) {
        unsigned p = part[j];
        uint4 u = G[(size_t)(p & 0xFFFFFFu) * 8 + l8];
        float* row = &acc[p >> 24][l8 * 8];
        const __half2* hp = (const __half2*)&u;
#pragma unroll
        for (int q = 0; q < 4; ++q) {
            float2 f = __half22float2(hp[q]);
            atomicAdd(row + 2 * q, f.x);
            atomicAdd(row + 2 * q + 1, f.y);
        }
    }
    __syncthreads();

    // ---- epilogue: self-term + scale + bias (+relu / direct store) ----
    {
        int r = t >> 1;
        int c0 = (t & 1) * 32;
        int v = v0 + r;
        float dv = (v < N) ? dinv[v] : 0.f;
        if ((t & 1) == 0) dvs[r] = dv;
        if (v < N) {
            const uint4* gs = G + (size_t)v * 8 + (c0 >> 3);
#pragma unroll
            for (int q4 = 0; q4 < 4; ++q4) {
                uint4 u = gs[q4];
                const __half2* hp = (const __half2*)&u;
                float4 bb0 = *(const float4*)&bias[c0 + q4 * 8];
                float4 bb1 = *(const float4*)&bias[c0 + q4 * 8 + 4];
                float* arow = &acc[r][c0 + q4 * 8];
                float s[8];
#pragma unroll
                for (int q = 0; q < 4; ++q) {
                    float2 f = __half22float2(hp[q]);
                    s[2 * q] = f.x; s[2 * q + 1] = f.y;
                }
                float o[8];
                o[0] = (arow[0] + s[0]) * dv + bb0.x;
                o[1] = (arow[1] + s[1]) * dv + bb0.y;
                o[2] = (arow[2] + s[2]) * dv + bb0.z;
                o[3] = (arow[3] + s[3]) * dv + bb0.w;
                o[4] = (arow[4] + s[4]) * dv + bb1.x;
                o[5] = (arow[5] + s[5]) * dv + bb1.y;
                o[6] = (arow[6] + s[6]) * dv + bb1.z;
                o[7] = (arow[7] + s[7]) * dv + bb1.w;
                if (MM) {
#pragma unroll
                    for (int i = 0; i < 8; ++i) arow[i] = fmaxf(o[i], 0.f);
                } else {
                    float* Of = (float*)Y + (size_t)v * F + c0 + q4 * 8;
                    *(float4*)Of = make_float4(o[0], o[1], o[2], o[3]);
                    *(float4*)(Of + 4) = make_float4(o[4], o[5], o[6], o[7]);
                }
            }
        }
    }
    if (MM) {
        __syncthreads();
        // ---- fused mm: g2 = (out1 @ W2) * dinv, 4 rows x 8 cols per thread ----
        int tx = t & 7, ty = t >> 3;   // rows ty, ty+32, ty+64, ty+96
        float a[4][8];
#pragma unroll
        for (int i = 0; i < 4; ++i)
#pragma unroll
            for (int c = 0; c < 8; ++c) a[i][c] = 0.f;
#pragma unroll 4
        for (int k4 = 0; k4 < 16; ++k4) {
            float4 xr[4];
#pragma unroll
            for (int i = 0; i < 4; ++i)
                xr[i] = *(const float4*)&acc[ty + 32 * i][k4 * 4];
#pragma unroll
            for (int kk = 0; kk < 4; ++kk) {
                int k = k4 * 4 + kk;
                float4 w0 = *(const float4*)&Ws[k * 64 + tx * 8];
                float4 w1 = *(const float4*)&Ws[k * 64 + tx * 8 + 4];
#pragma unroll
                for (int i = 0; i < 4; ++i) {
                    float xs = (&xr[i].x)[kk];
                    a[i][0] += xs * w0.x; a[i][1] += xs * w0.y;
                    a[i][2] += xs * w0.z; a[i][3] += xs * w0.w;
                    a[i][4] += xs * w1.x; a[i][5] += xs * w1.y;
                    a[i][6] += xs * w1.z; a[i][7] += xs * w1.w;
                }
            }
        }
#pragma unroll
        for (int i = 0; i < 4; ++i) {
            int rr = ty + 32 * i;
            int vv = v0 + rr;
            if (vv >= N) continue;
            float dv = dvs[rr];
            __half2 h[4];
#pragma unroll
            for (int q = 0; q < 4; ++q)
                h[q] = __floats2half2_rn(a[i][2 * q] * dv, a[i][2 * q + 1] * dv);
            *(uint4*)((__half*)Y + (size_t)vv * F + tx * 8) =
                *reinterpret_cast<uint4*>(h);
        }
    }
}

extern "C" void kernel_launch(void* const* d_in, const int* in_sizes, int n_in,
                              void* d_out, int out_size, void* d_ws, size_t ws_size,
                              hipStream_t stream) {
    const float* x  = (const float*)d_in[0];
    const int*   ei = (const int*)d_in[1];
    const float* W1 = (const float*)d_in[2];
    const float* b1 = (const float*)d_in[3];
    const float* W2 = (const float*)d_in[4];
    const float* b2 = (const float*)d_in[5];
    int N = in_sizes[0] / F;
    int E = in_sizes[1] / 2;
    const int* srcp = ei;
    const int* dstp = ei + E;
    float* out = (float*)d_out;
    int NB = (N + BN - 1) >> BSH;   // 782 for N=100k

    char* w = (char*)d_ws;
    auto align = [](size_t s) { return (s + 255) / 256 * 256; };
    unsigned* bcnt = (unsigned*)w;  w += align(NBMAX * 4);
    unsigned* part = (unsigned*)w;  w += align((size_t)NB << (CAPSH + 2));
    float*    dinv = (float*)w;     w += align((size_t)N * 4);
    __half2*  bufA = (__half2*)w;   w += align((size_t)N * F * 2);  // g1 (f16)
    __half*   bufC = (__half*)w;    w += align((size_t)N * F * 2);  // g2 (f16)

    hipMemsetAsync(bcnt, 0, (size_t)NB * 4, stream);
    partition_edges<<<(E + CHUNK - 1) / CHUNK, 256, 0, stream>>>(srcp, dstp, bcnt, part, E, NB);
    build_deg<<<NB, 256, 0, stream>>>(part, bcnt, dinv, N);

    // layer 1 linear: g1 = (x@W1)*dinv
    mm64_f16<<<(N + MMROWS - 1) / MMROWS, 256, 0, stream>>>(x, W1, dinv, bufA, N);
    // fused agg+mm: out1 = relu(dinv*(sum g1)+b1); g2 = (out1@W2)*dinv
    agg<1><<<NB, 256, 0, stream>>>(part, bcnt, (const uint4*)bufA, dinv, b1, W2, bufC, N);
    // final agg: out = dinv*(sum g2) + b2
    agg<0><<<NB, 256, 0, stream>>>(part, bcnt, (const uint4*)bufC, dinv, b2, nullptr, out, N);
}

// Round 10
// 181.463 us; speedup vs baseline: 5.4537x; 5.4537x over previous
//
#include <hip/hip_runtime.h>
#include <hip/hip_fp16.h>

#define F 64
#define NBMAX 1024     // max dst-buckets (256 nodes each) -> supports N <= 262144
#define CHUNK 4096     // edges per partition block
#define CAPSH 12       // bucket capacity = 4096 slots (mean fill ~2560, 30 sigma)
#define CAP (1 << CAPSH)
#define MMROWS 128
#define XT_PAD 132
#define GMN 64         // nodes per fused gather_mm block

// ---- A: dual-role kernel. Blocks [0,PG) partition edges into fixed-stride
// dst-buckets; blocks [PG,PG+MMG) compute g1 = x@W1 (fp16, UNSCALED — dinv
// applied later in build_bucket). The two tasks are data-independent.
__global__ __launch_bounds__(256) void part_mm(const int* __restrict__ src,
                                               const int* __restrict__ dst,
                                               unsigned* __restrict__ bcnt,
                                               unsigned* __restrict__ part,
                                               int E, int NB, int PG,
                                               const float* __restrict__ Xf,
                                               const float* __restrict__ W,
                                               __half2* __restrict__ Y, int N) {
    __shared__ float4 smem4[3136];   // 50176 B union
    int t = threadIdx.x;
    if ((int)blockIdx.x < PG) {
        // ---- partition role ----
        unsigned* lh    = (unsigned*)smem4;          // NBMAX
        unsigned* lbase = lh + NBMAX;                // NBMAX
        int e0 = blockIdx.x * CHUNK;
        int e1 = min(e0 + CHUNK, E);
        for (int b = t; b < NB; b += 256) lh[b] = 0;
        __syncthreads();
        for (int e = e0 + t; e < e1; e += 256)
            atomicAdd(&lh[((unsigned)dst[e]) >> 8], 1u);
        __syncthreads();
        for (int b = t; b < NB; b += 256) {
            unsigned c = lh[b];
            lbase[b] = c ? atomicAdd(&bcnt[b], c) : 0u;
            lh[b] = 0;  // reuse as local cursor
        }
        __syncthreads();
        for (int e = e0 + t; e < e1; e += 256) {
            unsigned d = (unsigned)dst[e];
            unsigned b = d >> 8;
            unsigned pos = lbase[b] + atomicAdd(&lh[b], 1u);
            if (pos < CAP)
                part[((size_t)b << CAPSH) + pos] = ((d & 255u) << 24) | (unsigned)src[e];
        }
        return;
    }
    // ---- mm role ----
    float* Ws = (float*)smem4;       // 4096 floats
    float* XT = Ws + 4096;           // 64*XT_PAD floats
    for (int i = t; i < 1024; i += 256)
        ((float4*)Ws)[i] = ((const float4*)W)[i];
    int row0 = ((int)blockIdx.x - PG) * MMROWS;
    for (int i = t; i < MMROWS * 16; i += 256) {
        int r = i >> 4, kc = (i & 15) * 4;
        float4 v = make_float4(0.f, 0.f, 0.f, 0.f);
        int gr = row0 + r;
        if (gr < N) v = *(const float4*)(Xf + (size_t)gr * F + kc);
        XT[(kc + 0) * XT_PAD + r] = v.x;
        XT[(kc + 1) * XT_PAD + r] = v.y;
        XT[(kc + 2) * XT_PAD + r] = v.z;
        XT[(kc + 3) * XT_PAD + r] = v.w;
    }
    __syncthreads();
    int ty = t >> 3, tx = t & 7;
    float acc[4][8];
#pragma unroll
    for (int i = 0; i < 4; ++i)
#pragma unroll
        for (int j = 0; j < 8; ++j) acc[i][j] = 0.f;
#pragma unroll 4
    for (int k = 0; k < 64; ++k) {
        float4 xr = *(const float4*)&XT[k * XT_PAD + ty * 4];
        float4 w0 = *(const float4*)&Ws[k * 64 + tx * 8];
        float4 w1 = *(const float4*)&Ws[k * 64 + tx * 8 + 4];
        const float* xv = &xr.x;
#pragma unroll
        for (int i = 0; i < 4; ++i) {
            float xs = xv[i];
            acc[i][0] += xs * w0.x; acc[i][1] += xs * w0.y;
            acc[i][2] += xs * w0.z; acc[i][3] += xs * w0.w;
            acc[i][4] += xs * w1.x; acc[i][5] += xs * w1.y;
            acc[i][6] += xs * w1.z; acc[i][7] += xs * w1.w;
        }
    }
#pragma unroll
    for (int i = 0; i < 4; ++i) {
        int gr = row0 + ty * 4 + i;
        if (gr >= N) continue;
        __half2 h[4];
#pragma unroll
        for (int j = 0; j < 4; ++j)
            h[j] = __floats2half2_rn(acc[i][2 * j], acc[i][2 * j + 1]);
        *reinterpret_cast<uint4*>(Y + (size_t)gr * 32 + tx * 4) =
            *reinterpret_cast<uint4*>(h);
    }
}

// ---- B: per-bucket CSR build; emits desc(start,deg,dinv), csr_src, and
// scales this bucket's g1 rows in-place by dinv (finishing mm1's epilogue).
__global__ __launch_bounds__(256) void build_bucket(const unsigned* __restrict__ part,
                                                    const unsigned* __restrict__ bcnt,
                                                    uint4* __restrict__ desc,
                                                    int* __restrict__ csr_src,
                                                    uint4* __restrict__ G,   // g1, scaled in place
                                                    int N) {
    __shared__ unsigned cnt[256], off[256], cur[256];
    __shared__ float dvl[256];
    int t = threadIdx.x;
    int b = blockIdx.x;
    unsigned m0 = (unsigned)b << CAPSH;
    unsigned m1 = m0 + min(bcnt[b], (unsigned)CAP);
    cnt[t] = 0;
    __syncthreads();
    for (unsigned j = m0 + t; j < m1; j += 256)
        atomicAdd(&cnt[part[j] >> 24], 1u);
    __syncthreads();
    off[t] = cnt[t];
    __syncthreads();
    for (int o = 1; o < 256; o <<= 1) {
        unsigned add = (t >= o) ? off[t - o] : 0u;
        __syncthreads();
        off[t] += add;
        __syncthreads();
    }
    unsigned excl = (t == 0) ? 0u : off[t - 1];
    __syncthreads();
    off[t] = excl;
    cur[t] = 0;
    int v0 = b << 8;
    int v = v0 + t;
    float di = rsqrtf((float)(cnt[t] + 1u));
    dvl[t] = di;
    if (v < N)
        desc[v] = make_uint4(m0 + excl, cnt[t], __float_as_uint(di), 0u);
    __syncthreads();
    for (unsigned j = m0 + t; j < m1; j += 256) {
        unsigned p = part[j];
        unsigned d = p >> 24;
        unsigned pos = atomicAdd(&cur[d], 1u);
        csr_src[m0 + off[d] + pos] = (int)(p & 0xFFFFFFu);
    }
    // ---- scale this bucket's 256 g1 rows by dinv (coalesced uint4 stream) ----
#pragma unroll
    for (int k = 0; k < 8; ++k) {
        int idx = t + k * 256;            // uint4 index within bucket (2048 total)
        int r = idx >> 3;
        int vv = v0 + r;
        if (vv >= N) continue;
        float dv = dvl[r];
        uint4 u = G[(size_t)v0 * 8 + idx];
        __half2* hp = (__half2*)&u;
#pragma unroll
        for (int q = 0; q < 4; ++q) {
            float2 f = __half22float2(hp[q]);
            hp[q] = __floats2half2_rn(f.x * dv, f.y * dv);
        }
        G[(size_t)v0 * 8 + idx] = u;
    }
}

__device__ __forceinline__ void acc8(float* a, const uint4& u) {
    const __half2* hp = reinterpret_cast<const __half2*>(&u);
#pragma unroll
    for (int q = 0; q < 4; ++q) {
        float2 f = __half22float2(hp[q]);
        a[2 * q] += f.x;
        a[2 * q + 1] += f.y;
    }
}

// ---- C FUSED: out1[v] = relu(dinv_v * (sum g1[s] + g1[v]) + b1) ; g2 = (out1@W2)*dinv ----
__global__ __launch_bounds__(256, 4) void gather_mm(const int* __restrict__ csr_src,
                                                    const uint4* __restrict__ desc,
                                                    const uint4* __restrict__ G,
                                                    const float* __restrict__ bias,
                                                    const float* __restrict__ W,
                                                    __half* __restrict__ Y, int N) {
    __shared__ float Ws[64 * 64];     // 16 KB
    __shared__ __half XT[64 * 72];    // 9 KB
    __shared__ float dvs[64];
    int t = threadIdx.x;
    for (int i = t; i < 1024; i += 256)
        ((float4*)Ws)[i] = ((const float4*)W)[i];
    int v0 = blockIdx.x * GMN;
    {   // ---- phase 1: gather ----
        int grp = t >> 2, l4 = t & 3;
        int v = v0 + grp;
        float acc[16];
#pragma unroll
        for (int i = 0; i < 16; ++i) acc[i] = 0.f;
        float dv = 0.f;
        if (v < N) {
            uint4 nd = desc[v];
            unsigned r0 = nd.x, r1 = nd.x + nd.y;
            dv = __uint_as_float(nd.z);
            size_t gb = (size_t)v * 8 + l4 * 2;
            uint4 sa = G[gb], sb = G[gb + 1];   // self-loop term
            acc8(acc, sa); acc8(acc + 8, sb);
            unsigned j = r0;
            for (; j + 4 <= r1; j += 4) {
                int s[4];
#pragma unroll
                for (int i = 0; i < 4; ++i) s[i] = csr_src[j + i];
                uint4 u[4][2];
#pragma unroll
                for (int i = 0; i < 4; ++i) {
                    size_t base = (size_t)s[i] * 8 + l4 * 2;
                    u[i][0] = G[base]; u[i][1] = G[base + 1];
                }
#pragma unroll
                for (int i = 0; i < 4; ++i) { acc8(acc, u[i][0]); acc8(acc + 8, u[i][1]); }
            }
            for (; j < r1; ++j) {
                size_t base = (size_t)csr_src[j] * 8 + l4 * 2;
                uint4 a = G[base], b = G[base + 1];
                acc8(acc, a); acc8(acc + 8, b);
            }
        }
        if (l4 == 0) dvs[grp] = dv;
        __half h[16];
#pragma unroll
        for (int q = 0; q < 4; ++q) {
            float4 bb = ((const float4*)bias)[l4 * 4 + q];
            float r0_ = fmaxf(acc[4 * q + 0] * dv + bb.x, 0.f);
            float r1_ = fmaxf(acc[4 * q + 1] * dv + bb.y, 0.f);
            float r2_ = fmaxf(acc[4 * q + 2] * dv + bb.z, 0.f);
            float r3_ = fmaxf(acc[4 * q + 3] * dv + bb.w, 0.f);
            ((__half2*)h)[2 * q + 0] = __floats2half2_rn(r0_, r1_);
            ((__half2*)h)[2 * q + 1] = __floats2half2_rn(r2_, r3_);
        }
        *(uint4*)&XT[grp * 72 + l4 * 16] = ((uint4*)h)[0];
        *(uint4*)&XT[grp * 72 + l4 * 16 + 8] = ((uint4*)h)[1];
    }
    __syncthreads();
    // ---- phase 2: mm (2 rows x 8 cols per thread) ----
    int tx = t & 7, ty = t >> 3;
    const __half2* Xa = (const __half2*)&XT[ty * 72];
    const __half2* Xb = (const __half2*)&XT[(ty + 32) * 72];
    float a0[8], a1[8];
#pragma unroll
    for (int i = 0; i < 8; ++i) { a0[i] = 0.f; a1[i] = 0.f; }
#pragma unroll 4
    for (int k2 = 0; k2 < 32; ++k2) {
        float2 f0 = __half22float2(Xa[k2]);
        float2 f1 = __half22float2(Xb[k2]);
        int k = 2 * k2;
        float4 w00 = *(const float4*)&Ws[k * 64 + tx * 8];
        float4 w01 = *(const float4*)&Ws[k * 64 + tx * 8 + 4];
        float4 w10 = *(const float4*)&Ws[(k + 1) * 64 + tx * 8];
        float4 w11 = *(const float4*)&Ws[(k + 1) * 64 + tx * 8 + 4];
        a0[0] += f0.x * w00.x + f0.y * w10.x; a0[1] += f0.x * w00.y + f0.y * w10.y;
        a0[2] += f0.x * w00.z + f0.y * w10.z; a0[3] += f0.x * w00.w + f0.y * w10.w;
        a0[4] += f0.x * w01.x + f0.y * w11.x; a0[5] += f0.x * w01.y + f0.y * w11.y;
        a0[6] += f0.x * w01.z + f0.y * w11.z; a0[7] += f0.x * w01.w + f0.y * w11.w;
        a1[0] += f1.x * w00.x + f1.y * w10.x; a1[1] += f1.x * w00.y + f1.y * w10.y;
        a1[2] += f1.x * w00.z + f1.y * w10.z; a1[3] += f1.x * w00.w + f1.y * w10.w;
        a1[4] += f1.x * w01.x + f1.y * w11.x; a1[5] += f1.x * w01.y + f1.y * w11.y;
        a1[6] += f1.x * w01.z + f1.y * w11.z; a1[7] += f1.x * w01.w + f1.y * w11.w;
    }
#pragma unroll
    for (int half_ = 0; half_ < 2; ++half_) {
        int r = ty + half_ * 32;
        int v = v0 + r;
        if (v >= N) continue;
        float dv = dvs[r];
        const float* a = half_ ? a1 : a0;
        __half2 h[4];
#pragma unroll
        for (int q = 0; q < 4; ++q)
            h[q] = __floats2half2_rn(a[2 * q] * dv, a[2 * q + 1] * dv);
        *(uint4*)(Y + (size_t)v * F + tx * 8) = *reinterpret_cast<uint4*>(h);
    }
}

// ---- D: final gather: out[v] = dinv[v]*(sum g2[s] + g2[v]) + b2 ; fp32 out ----
#define ACCUM8(u) { \
    const __half2* hp = reinterpret_cast<const __half2*>(&(u)); \
    _Pragma("unroll") \
    for (int q = 0; q < 4; ++q) { \
        float2 f = __half22float2(hp[q]); \
        acc[2 * q] += f.x; acc[2 * q + 1] += f.y; } }

__global__ __launch_bounds__(256) void gather_out(const int* __restrict__ csr_src,
                                                  const uint4* __restrict__ desc,
                                                  const uint4* __restrict__ G,
                                                  const float* __restrict__ bias,
                                                  float* __restrict__ O, int N) {
    int gid = blockIdx.x * 256 + threadIdx.x;
    int v = gid >> 3;
    if (v >= N) return;
    int l8 = gid & 7;
    uint4 nd = desc[v];
    unsigned r0 = nd.x;
    unsigned r1 = r0 + nd.y;
    float dv = __uint_as_float(nd.z);
    float acc[8];
#pragma unroll
    for (int i = 0; i < 8; ++i) acc[i] = 0.f;
    {
        uint4 u = G[(size_t)v * 8 + l8];  // self-loop term
        ACCUM8(u)
    }
    unsigned j = r0;
    for (; j + 8 <= r1; j += 8) {
        int s[8];
#pragma unroll
        for (int i = 0; i < 8; ++i) s[i] = csr_src[j + i];
        uint4 u[8];
#pragma unroll
        for (int i = 0; i < 8; ++i) u[i] = G[(size_t)s[i] * 8 + l8];
#pragma unroll
        for (int i = 0; i < 8; ++i) ACCUM8(u[i])
    }
    if (j + 4 <= r1) {
        int s[4];
#pragma unroll
        for (int i = 0; i < 4; ++i) s[i] = csr_src[j + i];
        uint4 u[4];
#pragma unroll
        for (int i = 0; i < 4; ++i) u[i] = G[(size_t)s[i] * 8 + l8];
#pragma unroll
        for (int i = 0; i < 4; ++i) ACCUM8(u[i])
        j += 4;
    }
    for (; j < r1; ++j) {
        uint4 u = G[(size_t)csr_src[j] * 8 + l8];
        ACCUM8(u)
    }
    float4 bb0 = ((const float4*)bias)[l8 * 2];
    float4 bb1 = ((const float4*)bias)[l8 * 2 + 1];
    float4* o = (float4*)O + (size_t)v * 16 + l8 * 2;
    o[0] = make_float4(acc[0] * dv + bb0.x, acc[1] * dv + bb0.y,
                       acc[2] * dv + bb0.z, acc[3] * dv + bb0.w);
    o[1] = make_float4(acc[4] * dv + bb1.x, acc[5] * dv + bb1.y,
                       acc[6] * dv + bb1.z, acc[7] * dv + bb1.w);
}
#undef ACCUM8

extern "C" void kernel_launch(void* const* d_in, const int* in_sizes, int n_in,
                              void* d_out, int out_size, void* d_ws, size_t ws_size,
                              hipStream_t stream) {
    const float* x  = (const float*)d_in[0];
    const int*   ei = (const int*)d_in[1];
    const float* W1 = (const float*)d_in[2];
    const float* b1 = (const float*)d_in[3];
    const float* W2 = (const float*)d_in[4];
    const float* b2 = (const float*)d_in[5];
    int N = in_sizes[0] / F;
    int E = in_sizes[1] / 2;
    const int* srcp = ei;
    const int* dstp = ei + E;
    float* out = (float*)d_out;
    int NB = (N + 255) >> 8;

    char* w = (char*)d_ws;
    auto align = [](size_t s) { return (s + 255) / 256 * 256; };
    unsigned* bcnt    = (unsigned*)w;  w += align(NBMAX * 4);
    unsigned* part    = (unsigned*)w;  w += align((size_t)NB << (CAPSH + 2));
    int*      csrsrc  = (int*)w;       w += align((size_t)NB << (CAPSH + 2));
    uint4*    desc    = (uint4*)w;     w += align((size_t)N * 16);
    __half2*  bufA    = (__half2*)w;   w += align((size_t)N * F * 2);  // g1 (f16)
    __half*   bufC    = (__half*)w;    w += align((size_t)N * F * 2);  // g2 (f16)

    hipMemsetAsync(bcnt, 0, (size_t)NB * 4, stream);

    int PG = (E + CHUNK - 1) / CHUNK;
    int MMG = (N + MMROWS - 1) / MMROWS;
    // A: partition edges (blocks 0..PG) + g1 = x@W1 unscaled (blocks PG..PG+MMG)
    part_mm<<<PG + MMG, 256, 0, stream>>>(srcp, dstp, bcnt, part, E, NB, PG,
                                          x, W1, (__half2*)bufA, N);
    // B: CSR build + desc/dinv + in-place dinv scaling of g1
    build_bucket<<<NB, 256, 0, stream>>>(part, bcnt, desc, csrsrc, (uint4*)bufA, N);
    // C: out1 = relu(dinv*(sum g1)+b1); g2 = (out1@W2)*dinv
    gather_mm<<<(N + GMN - 1) / GMN, 256, 0, stream>>>(csrsrc, desc, (const uint4*)bufA, b1, W2, bufC, N);
    // D: out = dinv*(sum g2) + b2
    gather_out<<<((size_t)N * 8 + 255) / 256, 256, 0, stream>>>(csrsrc, desc, (const uint4*)bufC, b2, out, N);
}

// Round 11
// 180.124 us; speedup vs baseline: 5.4942x; 1.0074x over previous
//
#include <hip/hip_runtime.h>
#include <hip/hip_fp16.h>

#define F 64
#define NBMAX 1024     // max dst-buckets (256 nodes each) -> supports N <= 262144
#define CHUNK 4096     // edges per partition block
#define CAPSH 13       // bucket capacity = 8192 slots (mean fill ~2560 + align pad <=768)
#define CAP (1 << CAPSH)
#define MMROWS 128
#define XT_PAD 132
#define GMN 64         // nodes per fused gather_mm block

// ---- A: dual-role kernel. Blocks [0,PG) partition edges into fixed-stride
// dst-buckets; blocks [PG,PG+MMG) compute g1 = x@W1 (fp16, UNSCALED — dinv
// applied later in build_bucket). The two tasks are data-independent.
__global__ __launch_bounds__(256) void part_mm(const int* __restrict__ src,
                                               const int* __restrict__ dst,
                                               unsigned* __restrict__ bcnt,
                                               unsigned* __restrict__ part,
                                               int E, int NB, int PG,
                                               const float* __restrict__ Xf,
                                               const float* __restrict__ W,
                                               __half2* __restrict__ Y, int N) {
    __shared__ float4 smem4[3136];   // 50176 B union
    int t = threadIdx.x;
    if ((int)blockIdx.x < PG) {
        // ---- partition role ----
        unsigned* lh    = (unsigned*)smem4;          // NBMAX
        unsigned* lbase = lh + NBMAX;                // NBMAX
        int e0 = blockIdx.x * CHUNK;
        int e1 = min(e0 + CHUNK, E);
        for (int b = t; b < NB; b += 256) lh[b] = 0;
        __syncthreads();
        for (int e = e0 + t; e < e1; e += 256)
            atomicAdd(&lh[((unsigned)dst[e]) >> 8], 1u);
        __syncthreads();
        for (int b = t; b < NB; b += 256) {
            unsigned c = lh[b];
            lbase[b] = c ? atomicAdd(&bcnt[b], c) : 0u;
            lh[b] = 0;  // reuse as local cursor
        }
        __syncthreads();
        for (int e = e0 + t; e < e1; e += 256) {
            unsigned d = (unsigned)dst[e];
            unsigned b = d >> 8;
            unsigned pos = lbase[b] + atomicAdd(&lh[b], 1u);
            if (pos < CAP)
                part[((size_t)b << CAPSH) + pos] = ((d & 255u) << 24) | (unsigned)src[e];
        }
        return;
    }
    // ---- mm role ----
    float* Ws = (float*)smem4;       // 4096 floats
    float* XT = Ws + 4096;           // 64*XT_PAD floats
    for (int i = t; i < 1024; i += 256)
        ((float4*)Ws)[i] = ((const float4*)W)[i];
    int row0 = ((int)blockIdx.x - PG) * MMROWS;
    for (int i = t; i < MMROWS * 16; i += 256) {
        int r = i >> 4, kc = (i & 15) * 4;
        float4 v = make_float4(0.f, 0.f, 0.f, 0.f);
        int gr = row0 + r;
        if (gr < N) v = *(const float4*)(Xf + (size_t)gr * F + kc);
        XT[(kc + 0) * XT_PAD + r] = v.x;
        XT[(kc + 1) * XT_PAD + r] = v.y;
        XT[(kc + 2) * XT_PAD + r] = v.z;
        XT[(kc + 3) * XT_PAD + r] = v.w;
    }
    __syncthreads();
    int ty = t >> 3, tx = t & 7;
    float acc[4][8];
#pragma unroll
    for (int i = 0; i < 4; ++i)
#pragma unroll
        for (int j = 0; j < 8; ++j) acc[i][j] = 0.f;
#pragma unroll 4
    for (int k = 0; k < 64; ++k) {
        float4 xr = *(const float4*)&XT[k * XT_PAD + ty * 4];
        float4 w0 = *(const float4*)&Ws[k * 64 + tx * 8];
        float4 w1 = *(const float4*)&Ws[k * 64 + tx * 8 + 4];
        const float* xv = &xr.x;
#pragma unroll
        for (int i = 0; i < 4; ++i) {
            float xs = xv[i];
            acc[i][0] += xs * w0.x; acc[i][1] += xs * w0.y;
            acc[i][2] += xs * w0.z; acc[i][3] += xs * w0.w;
            acc[i][4] += xs * w1.x; acc[i][5] += xs * w1.y;
            acc[i][6] += xs * w1.z; acc[i][7] += xs * w1.w;
        }
    }
#pragma unroll
    for (int i = 0; i < 4; ++i) {
        int gr = row0 + ty * 4 + i;
        if (gr >= N) continue;
        __half2 h[4];
#pragma unroll
        for (int j = 0; j < 4; ++j)
            h[j] = __floats2half2_rn(acc[i][2 * j], acc[i][2 * j + 1]);
        *reinterpret_cast<uint4*>(Y + (size_t)gr * 32 + tx * 4) =
            *reinterpret_cast<uint4*>(h);
    }
}

// ---- B: per-bucket CSR build. Per-node segments padded to 4-slot (16 B)
// alignment so gathers can use int4 index loads. Emits desc(start,deg,dinv),
// csr_src, and scales this bucket's g1 rows in-place by dinv.
__global__ __launch_bounds__(256) void build_bucket(const unsigned* __restrict__ part,
                                                    const unsigned* __restrict__ bcnt,
                                                    uint4* __restrict__ desc,
                                                    int* __restrict__ csr_src,
                                                    uint4* __restrict__ G,   // g1, scaled in place
                                                    int N) {
    __shared__ unsigned cnt[256], off[256], cur[256];
    __shared__ float dvl[256];
    int t = threadIdx.x;
    int b = blockIdx.x;
    unsigned m0 = (unsigned)b << CAPSH;
    unsigned m1 = m0 + min(bcnt[b], (unsigned)CAP);
    cnt[t] = 0;
    __syncthreads();
    for (unsigned j = m0 + t; j < m1; j += 256)
        atomicAdd(&cnt[part[j] >> 24], 1u);
    __syncthreads();
    off[t] = (cnt[t] + 3u) & ~3u;   // pad each segment to multiple of 4 slots
    __syncthreads();
    for (int o = 1; o < 256; o <<= 1) {
        unsigned add = (t >= o) ? off[t - o] : 0u;
        __syncthreads();
        off[t] += add;
        __syncthreads();
    }
    unsigned excl = (t == 0) ? 0u : off[t - 1];
    __syncthreads();
    off[t] = excl;
    cur[t] = 0;
    int v0 = b << 8;
    int v = v0 + t;
    float di = rsqrtf((float)(cnt[t] + 1u));
    dvl[t] = di;
    if (v < N)
        desc[v] = make_uint4(m0 + excl, cnt[t], __float_as_uint(di), 0u);
    __syncthreads();
    for (unsigned j = m0 + t; j < m1; j += 256) {
        unsigned p = part[j];
        unsigned d = p >> 24;
        unsigned pos = atomicAdd(&cur[d], 1u);
        csr_src[m0 + off[d] + pos] = (int)(p & 0xFFFFFFu);
    }
    // ---- scale this bucket's 256 g1 rows by dinv (coalesced uint4 stream) ----
#pragma unroll
    for (int k = 0; k < 8; ++k) {
        int idx = t + k * 256;            // uint4 index within bucket (2048 total)
        int r = idx >> 3;
        int vv = v0 + r;
        if (vv >= N) continue;
        float dv = dvl[r];
        uint4 u = G[(size_t)v0 * 8 + idx];
        __half2* hp = (__half2*)&u;
#pragma unroll
        for (int q = 0; q < 4; ++q) {
            float2 f = __half22float2(hp[q]);
            hp[q] = __floats2half2_rn(f.x * dv, f.y * dv);
        }
        G[(size_t)v0 * 8 + idx] = u;
    }
}

__device__ __forceinline__ void acc8(float* a, const uint4& u) {
    const __half2* hp = reinterpret_cast<const __half2*>(&u);
#pragma unroll
    for (int q = 0; q < 4; ++q) {
        float2 f = __half22float2(hp[q]);
        a[2 * q] += f.x;
        a[2 * q + 1] += f.y;
    }
}

// ---- C FUSED: out1[v] = relu(dinv_v * (sum g1[s] + g1[v]) + b1) ; g2 = (out1@W2)*dinv ----
__global__ __launch_bounds__(256, 4) void gather_mm(const int* __restrict__ csr_src,
                                                    const uint4* __restrict__ desc,
                                                    const uint4* __restrict__ G,
                                                    const float* __restrict__ bias,
                                                    const float* __restrict__ W,
                                                    __half* __restrict__ Y, int N) {
    __shared__ float Ws[64 * 64];     // 16 KB
    __shared__ __half XT[64 * 72];    // 9 KB
    __shared__ float dvs[64];
    int t = threadIdx.x;
    for (int i = t; i < 1024; i += 256)
        ((float4*)Ws)[i] = ((const float4*)W)[i];
    int v0 = blockIdx.x * GMN;
    {   // ---- phase 1: gather (int4 index loads; r0 is 16 B aligned) ----
        int grp = t >> 2, l4 = t & 3;
        int v = v0 + grp;
        float acc[16];
#pragma unroll
        for (int i = 0; i < 16; ++i) acc[i] = 0.f;
        float dv = 0.f;
        if (v < N) {
            uint4 nd = desc[v];
            unsigned r0 = nd.x, r1 = nd.x + nd.y;
            dv = __uint_as_float(nd.z);
            size_t gb = (size_t)v * 8 + l4 * 2;
            uint4 sa = G[gb], sb = G[gb + 1];   // self-loop term
            acc8(acc, sa); acc8(acc + 8, sb);
            unsigned j = r0;
            for (; j + 4 <= r1; j += 4) {
                int4 s4 = *(const int4*)(csr_src + j);
                const int s[4] = { s4.x, s4.y, s4.z, s4.w };
                uint4 u[4][2];
#pragma unroll
                for (int i = 0; i < 4; ++i) {
                    size_t base = (size_t)s[i] * 8 + l4 * 2;
                    u[i][0] = G[base]; u[i][1] = G[base + 1];
                }
#pragma unroll
                for (int i = 0; i < 4; ++i) { acc8(acc, u[i][0]); acc8(acc + 8, u[i][1]); }
            }
            for (; j < r1; ++j) {
                size_t base = (size_t)csr_src[j] * 8 + l4 * 2;
                uint4 a = G[base], b = G[base + 1];
                acc8(acc, a); acc8(acc + 8, b);
            }
        }
        if (l4 == 0) dvs[grp] = dv;
        __half h[16];
#pragma unroll
        for (int q = 0; q < 4; ++q) {
            float4 bb = ((const float4*)bias)[l4 * 4 + q];
            float r0_ = fmaxf(acc[4 * q + 0] * dv + bb.x, 0.f);
            float r1_ = fmaxf(acc[4 * q + 1] * dv + bb.y, 0.f);
            float r2_ = fmaxf(acc[4 * q + 2] * dv + bb.z, 0.f);
            float r3_ = fmaxf(acc[4 * q + 3] * dv + bb.w, 0.f);
            ((__half2*)h)[2 * q + 0] = __floats2half2_rn(r0_, r1_);
            ((__half2*)h)[2 * q + 1] = __floats2half2_rn(r2_, r3_);
        }
        *(uint4*)&XT[grp * 72 + l4 * 16] = ((uint4*)h)[0];
        *(uint4*)&XT[grp * 72 + l4 * 16 + 8] = ((uint4*)h)[1];
    }
    __syncthreads();
    // ---- phase 2: mm (2 rows x 8 cols per thread) ----
    int tx = t & 7, ty = t >> 3;
    const __half2* Xa = (const __half2*)&XT[ty * 72];
    const __half2* Xb = (const __half2*)&XT[(ty + 32) * 72];
    float a0[8], a1[8];
#pragma unroll
    for (int i = 0; i < 8; ++i) { a0[i] = 0.f; a1[i] = 0.f; }
#pragma unroll 4
    for (int k2 = 0; k2 < 32; ++k2) {
        float2 f0 = __half22float2(Xa[k2]);
        float2 f1 = __half22float2(Xb[k2]);
        int k = 2 * k2;
        float4 w00 = *(const float4*)&Ws[k * 64 + tx * 8];
        float4 w01 = *(const float4*)&Ws[k * 64 + tx * 8 + 4];
        float4 w10 = *(const float4*)&Ws[(k + 1) * 64 + tx * 8];
        float4 w11 = *(const float4*)&Ws[(k + 1) * 64 + tx * 8 + 4];
        a0[0] += f0.x * w00.x + f0.y * w10.x; a0[1] += f0.x * w00.y + f0.y * w10.y;
        a0[2] += f0.x * w00.z + f0.y * w10.z; a0[3] += f0.x * w00.w + f0.y * w10.w;
        a0[4] += f0.x * w01.x + f0.y * w11.x; a0[5] += f0.x * w01.y + f0.y * w11.y;
        a0[6] += f0.x * w01.z + f0.y * w11.z; a0[7] += f0.x * w01.w + f0.y * w11.w;
        a1[0] += f1.x * w00.x + f1.y * w10.x; a1[1] += f1.x * w00.y + f1.y * w10.y;
        a1[2] += f1.x * w00.z + f1.y * w10.z; a1[3] += f1.x * w00.w + f1.y * w10.w;
        a1[4] += f1.x * w01.x + f1.y * w11.x; a1[5] += f1.x * w01.y + f1.y * w11.y;
        a1[6] += f1.x * w01.z + f1.y * w11.z; a1[7] += f1.x * w01.w + f1.y * w11.w;
    }
#pragma unroll
    for (int half_ = 0; half_ < 2; ++half_) {
        int r = ty + half_ * 32;
        int v = v0 + r;
        if (v >= N) continue;
        float dv = dvs[r];
        const float* a = half_ ? a1 : a0;
        __half2 h[4];
#pragma unroll
        for (int q = 0; q < 4; ++q)
            h[q] = __floats2half2_rn(a[2 * q] * dv, a[2 * q + 1] * dv);
        *(uint4*)(Y + (size_t)v * F + tx * 8) = *reinterpret_cast<uint4*>(h);
    }
}

// ---- D: final gather: out[v] = dinv[v]*(sum g2[s] + g2[v]) + b2 ; fp32 out ----
#define ACCUM8(u) { \
    const __half2* hp = reinterpret_cast<const __half2*>(&(u)); \
    _Pragma("unroll") \
    for (int q = 0; q < 4; ++q) { \
        float2 f = __half22float2(hp[q]); \
        acc[2 * q] += f.x; acc[2 * q + 1] += f.y; } }

__global__ __launch_bounds__(256) void gather_out(const int* __restrict__ csr_src,
                                                  const uint4* __restrict__ desc,
                                                  const uint4* __restrict__ G,
                                                  const float* __restrict__ bias,
                                                  float* __restrict__ O, int N) {
    int gid = blockIdx.x * 256 + threadIdx.x;
    int v = gid >> 3;
    if (v >= N) return;
    int l8 = gid & 7;
    uint4 nd = desc[v];
    unsigned r0 = nd.x;
    unsigned r1 = r0 + nd.y;
    float dv = __uint_as_float(nd.z);
    float acc[8];
#pragma unroll
    for (int i = 0; i < 8; ++i) acc[i] = 0.f;
    {
        uint4 u = G[(size_t)v * 8 + l8];  // self-loop term
        ACCUM8(u)
    }
    unsigned j = r0;   // 16 B aligned
    for (; j + 8 <= r1; j += 8) {
        int4 sa = *(const int4*)(csr_src + j);
        int4 sb = *(const int4*)(csr_src + j + 4);
        const int s[8] = { sa.x, sa.y, sa.z, sa.w, sb.x, sb.y, sb.z, sb.w };
        uint4 u[8];
#pragma unroll
        for (int i = 0; i < 8; ++i) u[i] = G[(size_t)s[i] * 8 + l8];
#pragma unroll
        for (int i = 0; i < 8; ++i) ACCUM8(u[i])
    }
    if (j + 4 <= r1) {
        int4 sa = *(const int4*)(csr_src + j);
        const int s[4] = { sa.x, sa.y, sa.z, sa.w };
        uint4 u[4];
#pragma unroll
        for (int i = 0; i < 4; ++i) u[i] = G[(size_t)s[i] * 8 + l8];
#pragma unroll
        for (int i = 0; i < 4; ++i) ACCUM8(u[i])
        j += 4;
    }
    for (; j < r1; ++j) {
        uint4 u = G[(size_t)csr_src[j] * 8 + l8];
        ACCUM8(u)
    }
    float4 bb0 = ((const float4*)bias)[l8 * 2];
    float4 bb1 = ((const float4*)bias)[l8 * 2 + 1];
    float4* o = (float4*)O + (size_t)v * 16 + l8 * 2;
    o[0] = make_float4(acc[0] * dv + bb0.x, acc[1] * dv + bb0.y,
                       acc[2] * dv + bb0.z, acc[3] * dv + bb0.w);
    o[1] = make_float4(acc[4] * dv + bb1.x, acc[5] * dv + bb1.y,
                       acc[6] * dv + bb1.z, acc[7] * dv + bb1.w);
}
#undef ACCUM8

extern "C" void kernel_launch(void* const* d_in, const int* in_sizes, int n_in,
                              void* d_out, int out_size, void* d_ws, size_t ws_size,
                              hipStream_t stream) {
    const float* x  = (const float*)d_in[0];
    const int*   ei = (const int*)d_in[1];
    const float* W1 = (const float*)d_in[2];
    const float* b1 = (const float*)d_in[3];
    const float* W2 = (const float*)d_in[4];
    const float* b2 = (const float*)d_in[5];
    int N = in_sizes[0] / F;
    int E = in_sizes[1] / 2;
    const int* srcp = ei;
    const int* dstp = ei + E;
    float* out = (float*)d_out;
    int NB = (N + 255) >> 8;

    char* w = (char*)d_ws;
    auto align = [](size_t s) { return (s + 255) / 256 * 256; };
    unsigned* bcnt    = (unsigned*)w;  w += align(NBMAX * 4);
    unsigned* part    = (unsigned*)w;  w += align((size_t)NB << (CAPSH + 2));
    int*      csrsrc  = (int*)w;       w += align((size_t)NB << (CAPSH + 2));
    uint4*    desc    = (uint4*)w;     w += align((size_t)N * 16);
    __half2*  bufA    = (__half2*)w;   w += align((size_t)N * F * 2);  // g1 (f16)
    __half*   bufC    = (__half*)w;    w += align((size_t)N * F * 2);  // g2 (f16)

    hipMemsetAsync(bcnt, 0, (size_t)NB * 4, stream);

    int PG = (E + CHUNK - 1) / CHUNK;
    int MMG = (N + MMROWS - 1) / MMROWS;
    // A: partition edges (blocks 0..PG) + g1 = x@W1 unscaled (blocks PG..PG+MMG)
    part_mm<<<PG + MMG, 256, 0, stream>>>(srcp, dstp, bcnt, part, E, NB, PG,
                                          x, W1, (__half2*)bufA, N);
    // B: CSR build (4-aligned segments) + desc + in-place dinv scaling of g1
    build_bucket<<<NB, 256, 0, stream>>>(part, bcnt, desc, csrsrc, (uint4*)bufA, N);
    // C: out1 = relu(dinv*(sum g1)+b1); g2 = (out1@W2)*dinv
    gather_mm<<<(N + GMN - 1) / GMN, 256, 0, stream>>>(csrsrc, desc, (const uint4*)bufA, b1, W2, bufC, N);
    // D: out = dinv*(sum g2) + b2
    gather_out<<<((size_t)N * 8 + 255) / 256, 256, 0, stream>>>(csrsrc, desc, (const uint4*)bufC, b2, out, N);
}